// Round 3
// baseline (548.542 us; speedup 1.0000x reference)
//
#include <hip/hip_runtime.h>
#include <hip/hip_bf16.h>
#include <math.h>

#define QQ   10
#define CC   64
#define HWSZ 65536          // H*W
#define NPOS 655360         // Q*H*W
#define LL   64800          // L_H*L_W
#define KK   9

// ---------------------------------------------------------------------------
// Kernel 1: transpose x (bq, c, hw) -> xt (b, n, c) in BF16  [n = q*HW + hw]
//           fused with per-n channel sum/max (fp32, packed float2).
// Grid: (1024, 20) blocks of 256. Block: 64(hw) x 64(c) tile.
// Phase A stores 8 B/lane (4 bf16) -> 512 B per wave-instruction.
// ---------------------------------------------------------------------------
__global__ __launch_bounds__(256) void k_transpose_stats(
    const float* __restrict__ x, __hip_bfloat16* __restrict__ xt,
    float2* __restrict__ stats) {
  __shared__ float tile[64][65];   // [c][hw], +1 pad
  __shared__ float sred[4][64];
  __shared__ float mred[4][64];
  const int t    = threadIdx.x;
  const int lane = t & 63;
  const int wid  = t >> 6;
  const int hw_base = blockIdx.x * 64;
  const int bq = blockIdx.y;            // 0..19
  const float* xp = x + (size_t)bq * CC * HWSZ + hw_base;

  // Load 64x64 tile, float4 per thread x4 (coalesced 16B/lane)
#pragma unroll
  for (int i = 0; i < 4; ++i) {
    int linear = t + i * 256;           // 0..1023
    int row  = linear >> 4;             // channel
    int col4 = (linear & 15) << 2;      // hw offset within tile
    const float4 v = *(const float4*)(xp + (size_t)row * HWSZ + col4);
    tile[row][col4 + 0] = v.x;
    tile[row][col4 + 1] = v.y;
    tile[row][col4 + 2] = v.z;
    tile[row][col4 + 3] = v.w;
  }
  __syncthreads();

  const int b = bq / QQ, q = bq % QQ;
  const size_t n_base = (size_t)q * HWSZ + hw_base;
  __hip_bfloat16* xtb = xt + (size_t)b * NPOS * CC;

  // Phase A: transposed bf16 store. lane -> (sub-position, channel-quad):
  // 16 lanes x 8 B cover one position's 64 channels... 4 positions per instr.
  const int c0  = (lane & 15) << 2;     // channel quad base
  const int sub = lane >> 4;            // position sub-offset 0..3
#pragma unroll
  for (int j = 0; j < 4; ++j) {
    const int p = wid * 16 + j * 4 + sub;
    const float v0 = tile[c0 + 0][p];
    const float v1 = tile[c0 + 1][p];
    const float v2 = tile[c0 + 2][p];
    const float v3 = tile[c0 + 3][p];
    union { __hip_bfloat162 h; unsigned u; } lo, hi;
    lo.h = __float22bfloat162_rn(make_float2(v0, v1));
    hi.h = __float22bfloat162_rn(make_float2(v2, v3));
    uint2 pk; pk.x = lo.u; pk.y = hi.u;
    *(uint2*)(xtb + (n_base + p) * CC + c0) = pk;
  }

  // Phase B: per-position channel sum/max (partial per wave, then wave 0).
  {
    const int pos = lane;
    const int cc0 = wid * 16;
    float psum = tile[cc0][pos];
    float pmax = psum;
#pragma unroll
    for (int c = 1; c < 16; ++c) {
      const float v = tile[cc0 + c][pos];
      psum += v;
      pmax = fmaxf(pmax, v);
    }
    sred[wid][pos] = psum;
    mred[wid][pos] = pmax;
  }
  __syncthreads();
  if (wid == 0) {
    const int pos = lane;
    float2 sm;
    sm.x = sred[0][pos] + sred[1][pos] + sred[2][pos] + sred[3][pos];
    sm.y = fmaxf(fmaxf(mred[0][pos], mred[1][pos]),
                 fmaxf(mred[2][pos], mred[3][pos]));
    stats[(size_t)b * NPOS + n_base + pos] = sm;
  }
}

// ---------------------------------------------------------------------------
// Kernel 2: attention weights. Thread per (b,l): 9 stat gathers (8 B each),
// 162 fma against LDS-staged att params, 9 sigmoids -> watt[b*LL+l][9].
// All 64 lanes productive (vs 9/64 in the fused version).
// ---------------------------------------------------------------------------
__global__ __launch_bounds__(256) void k_att(
    const float2* __restrict__ stats, const int* __restrict__ idx,
    const float* __restrict__ att_w, const float* __restrict__ att_b,
    float* __restrict__ watt) {
  __shared__ float aw[2 * KK * KK + KK];   // 162 att_w + 9 att_b
  const int t = threadIdx.x;
  if (t < 2 * KK * KK) aw[t] = att_w[t];
  else if (t < 2 * KK * KK + KK) aw[t] = att_b[t - 2 * KK * KK];
  __syncthreads();

  const int tg = blockIdx.x * 256 + t;
  if (tg >= 2 * LL) return;
  const int b = tg / LL;
  const int l = tg - b * LL;
  const float2* st = stats + (size_t)b * NPOS;

  float mean[KK], mx[KK];
#pragma unroll
  for (int k = 0; k < KK; ++k) {
    const int n = idx[l * KK + k];
    const float2 sm = st[n];
    mean[k] = sm.x * (1.0f / 64.0f);
    mx[k]   = sm.y;
  }

  float* wp = watt + (size_t)tg * KK;
#pragma unroll
  for (int h = 0; h < KK; ++h) {
    float logit = aw[2 * KK * KK + h];
#pragma unroll
    for (int k = 0; k < KK; ++k) {
      logit = fmaf(mean[k], aw[h * 2 * KK + k], logit);
      logit = fmaf(mx[k],   aw[h * 2 * KK + KK + k], logit);
    }
    wp[h] = 1.0f + 1.0f / (1.0f + __expf(-logit));
  }
}

// ---------------------------------------------------------------------------
// Kernel 3: weighted gather-reduce -> out (b,c,l).
// Wave handles 2 l's at once: lanes 0-31 = l0, 32-63 = l1; each lane owns
// 2 channels (packed uint = 2 bf16). Gather = 256 B per wave-instruction.
// Block = 4 waves x 8 l = 32 l. Grid b-major (LLC residency of xt slice).
// ---------------------------------------------------------------------------
__global__ __launch_bounds__(256) void k_gather_out(
    const __hip_bfloat16* __restrict__ xt, const int* __restrict__ idx,
    const float* __restrict__ watt, const float* __restrict__ tc_w,
    const float* __restrict__ tc_b, float* __restrict__ out) {
  const int blk    = blockIdx.x;
  const int b      = blk / (LL / 32);
  const int l_base = (blk % (LL / 32)) * 32;
  const int t = threadIdx.x, lane = t & 63, wid = t >> 6;
  const int half = lane >> 5, lh = lane & 31;
  __shared__ float res[64][33];        // [c][l-within-block], padded

  float tw0[KK], tw1[KK];
#pragma unroll
  for (int k = 0; k < KK; ++k) {
    tw0[k] = tc_w[(2 * lh) * KK + k];
    tw1[k] = tc_w[(2 * lh + 1) * KK + k];
  }
  const float tb0 = tc_b[2 * lh];
  const float tb1 = tc_b[2 * lh + 1];

  const unsigned* xtb = (const unsigned*)(xt + (size_t)b * NPOS * CC);
  const float* wb = watt + (size_t)b * LL * KK;
  const int kl = lh < KK ? lh : KK - 1;

#pragma unroll
  for (int j = 0; j < 4; ++j) {
    const int myl = l_base + wid * 8 + j * 2 + half;
    // lanes 0-8 (l0) and 32-40 (l1) hold the 9 idx/w values
    const int   nk = idx[myl * KK + kl];
    const float wv = wb[myl * KK + kl];

    float a0 = 0.0f, a1 = 0.0f;
#pragma unroll
    for (int k = 0; k < KK; ++k) {
      const int   src = half * 32 + k;
      const int   n   = __shfl(nk, src);
      const float wk  = __shfl(wv, src);
      const unsigned u = xtb[(size_t)n * 32 + lh];   // 2 bf16, coalesced 128B/half-wave
      const float f0 = __uint_as_float(u << 16);
      const float f1 = __uint_as_float(u & 0xffff0000u);
      a0 = fmaf(wk * tw0[k], f0, a0);
      a1 = fmaf(wk * tw1[k], f1, a1);
    }
    const int li = wid * 8 + j * 2 + half;
    res[2 * lh][li]     = a0 + tb0;
    res[2 * lh + 1][li] = a1 + tb1;
  }
  __syncthreads();

  // Output: 64 c x 32 l tile, float4 per store, 2 per thread.
  const int c  = t >> 2;
  const int q4 = t & 3;
#pragma unroll
  for (int rep = 0; rep < 2; ++rep) {
    const int lo = rep * 16 + q4 * 4;
    float4 o;
    o.x = res[c][lo + 0];
    o.y = res[c][lo + 1];
    o.z = res[c][lo + 2];
    o.w = res[c][lo + 3];
    *(float4*)(out + ((size_t)b * CC + c) * LL + l_base + lo) = o;
  }
}

extern "C" void kernel_launch(void* const* d_in, const int* in_sizes, int n_in,
                              void* d_out, int out_size, void* d_ws, size_t ws_size,
                              hipStream_t stream) {
  const float* x     = (const float*)d_in[0];
  const int*   idx   = (const int*)d_in[1];
  const float* att_w = (const float*)d_in[2];
  const float* att_b = (const float*)d_in[3];
  const float* tc_w  = (const float*)d_in[4];
  const float* tc_b  = (const float*)d_in[5];
  float* out = (float*)d_out;

  // ws carve: xt bf16 (2*N*64, 168 MB) | stats float2 (2*N, 10.5 MB)
  //           | watt (2*L*9 f32, 4.7 MB)
  __hip_bfloat16* xt = (__hip_bfloat16*)d_ws;
  float2* stats = (float2*)(xt + (size_t)2 * NPOS * CC);
  float* watt = (float*)(stats + (size_t)2 * NPOS);

  dim3 g1(HWSZ / 64, 2 * QQ);
  k_transpose_stats<<<g1, 256, 0, stream>>>(x, xt, stats);

  dim3 g2((2 * LL + 255) / 256);
  k_att<<<g2, 256, 0, stream>>>(stats, idx, att_w, att_b, watt);

  dim3 g3(2 * (LL / 32));
  k_gather_out<<<g3, 256, 0, stream>>>(xt, idx, watt, tc_w, tc_b, out);
}

// Round 4
// 519.152 us; speedup vs baseline: 1.0566x; 1.0566x over previous
//
#include <hip/hip_runtime.h>
#include <hip/hip_bf16.h>
#include <math.h>

#define QQ   10
#define CC   64
#define HWSZ 65536          // H*W
#define NPOS 655360         // Q*H*W
#define LL   64800          // L_H*L_W
#define KK   9

// ---------------------------------------------------------------------------
// Mask build: mask[n] = 1 iff n appears in idx. Batch-independent (idx shared).
// ---------------------------------------------------------------------------
__global__ __launch_bounds__(256) void k_mask_zero(uint4* __restrict__ m) {
  m[blockIdx.x * 256 + threadIdx.x] = make_uint4(0u, 0u, 0u, 0u);
}

__global__ __launch_bounds__(256) void k_mask_set(
    const int* __restrict__ idx, unsigned char* __restrict__ m) {
  const int i = blockIdx.x * 256 + threadIdx.x;
  if (i < LL * KK) m[idx[i]] = 1;   // benign same-value races
}

// ---------------------------------------------------------------------------
// Kernel 1: transpose x (bq, c, hw) -> xt (b, n, c) in BF16, fused per-n
// channel sum/max (float2 stats). Stores PREDICATED on mask[n] — ~41% of
// positions are never gathered, their writes are skipped (exec-masked lanes
// produce no HBM traffic).
// ---------------------------------------------------------------------------
__global__ __launch_bounds__(256) void k_transpose_stats(
    const float* __restrict__ x, const unsigned char* __restrict__ mask,
    __hip_bfloat16* __restrict__ xt, float2* __restrict__ stats) {
  __shared__ float tile[64][65];   // [c][hw], +1 pad
  __shared__ float sred[4][64];
  __shared__ float mred[4][64];
  const int t    = threadIdx.x;
  const int lane = t & 63;
  const int wid  = t >> 6;
  const int hw_base = blockIdx.x * 64;
  const int bq = blockIdx.y;            // 0..19
  const float* xp = x + (size_t)bq * CC * HWSZ + hw_base;

#pragma unroll
  for (int i = 0; i < 4; ++i) {
    int linear = t + i * 256;           // 0..1023
    int row  = linear >> 4;             // channel
    int col4 = (linear & 15) << 2;      // hw offset
    const float4 v = *(const float4*)(xp + (size_t)row * HWSZ + col4);
    tile[row][col4 + 0] = v.x;
    tile[row][col4 + 1] = v.y;
    tile[row][col4 + 2] = v.z;
    tile[row][col4 + 3] = v.w;
  }
  __syncthreads();

  const int b = bq / QQ, q = bq % QQ;
  const size_t n_base = (size_t)q * HWSZ + hw_base;
  __hip_bfloat16* xtb = xt + (size_t)b * NPOS * CC;

  // Phase A: packed transposed store, 8 B/lane (4 bf16) = 2 KB/wave-instr.
  const int c0  = (lane & 15) << 2;     // channel quad base
  const int sub = lane >> 4;            // position sub-offset 0..3
#pragma unroll
  for (int j = 0; j < 4; ++j) {
    const int p = wid * 16 + j * 4 + sub;
    if (mask[n_base + p]) {
      const float v0 = tile[c0 + 0][p];
      const float v1 = tile[c0 + 1][p];
      const float v2 = tile[c0 + 2][p];
      const float v3 = tile[c0 + 3][p];
      union { __hip_bfloat162 h; unsigned u; } lo, hi;
      lo.h = __float22bfloat162_rn(make_float2(v0, v1));
      hi.h = __float22bfloat162_rn(make_float2(v2, v3));
      uint2 pk; pk.x = lo.u; pk.y = hi.u;
      *(uint2*)(xtb + (n_base + p) * CC + c0) = pk;
    }
  }

  // Phase B: per-position channel sum/max (wave partials, wave 0 combines).
  {
    const int pos = lane;
    const int cc0 = wid * 16;
    float psum = tile[cc0][pos];
    float pmax = psum;
#pragma unroll
    for (int c = 1; c < 16; ++c) {
      const float v = tile[cc0 + c][pos];
      psum += v;
      pmax = fmaxf(pmax, v);
    }
    sred[wid][pos] = psum;
    mred[wid][pos] = pmax;
  }
  __syncthreads();
  if (wid == 0) {
    const int pos = lane;
    if (mask[n_base + pos]) {
      float2 sm;
      sm.x = sred[0][pos] + sred[1][pos] + sred[2][pos] + sred[3][pos];
      sm.y = fmaxf(fmaxf(mred[0][pos], mred[1][pos]),
                   fmaxf(mred[2][pos], mred[3][pos]));
      stats[(size_t)b * NPOS + n_base + pos] = sm;
    }
  }
}

// ---------------------------------------------------------------------------
// Kernel 2 (fused): per block = 32 l's of one batch.
//  step 1a: 288 threadsful gather (n, stats) for (l,k) -> LDS
//  step 1b: 288 logits (all lanes productive, params in LDS) -> w -> LDS
//  step 2 : gather loop; (n,w) via one broadcast ds_read_b64, no shuffles;
//           wave handles 2 l's (half-waves), lane owns 2 packed channels.
//  step 3 : float4 coalesced out.
// ---------------------------------------------------------------------------
__global__ __launch_bounds__(256) void k_gather_out(
    const __hip_bfloat16* __restrict__ xt, const float2* __restrict__ stats,
    const int* __restrict__ idx, const float* __restrict__ att_w,
    const float* __restrict__ att_b, const float* __restrict__ tc_w,
    const float* __restrict__ tc_b, float* __restrict__ out) {
  const int blk    = blockIdx.x;
  const int b      = blk / (LL / 32);
  const int l_base = (blk % (LL / 32)) * 32;
  const int t = threadIdx.x, lane = t & 63, wid = t >> 6;
  const int half = lane >> 5, lh = lane & 31;
  __shared__ float  res[64][33];        // [c][l-in-block]
  __shared__ float2 nw[32][KK];         // .x = n (int bits), .y = att weight
  __shared__ float  sms[32][KK], smm[32][KK];
  __shared__ float  aw[2 * KK * KK + KK];

  if (t < 2 * KK * KK + KK)
    aw[t] = (t < 2 * KK * KK) ? att_w[t] : att_b[t - 2 * KK * KK];

  const float2* stb = stats + (size_t)b * NPOS;
  // step 1a
  for (int i = t; i < 32 * KK; i += 256) {
    const int ll = i / KK, k = i - ll * KK;
    const int n = idx[(l_base + ll) * KK + k];
    nw[ll][k].x = __int_as_float(n);
    const float2 sm = stb[n];
    sms[ll][k] = sm.x;
    smm[ll][k] = sm.y;
  }
  __syncthreads();

  // step 1b
  for (int i = t; i < 32 * KK; i += 256) {
    const int ll = i / KK, h = i - ll * KK;
    float logit = aw[2 * KK * KK + h];
#pragma unroll
    for (int k = 0; k < KK; ++k) {
      logit = fmaf(sms[ll][k] * (1.0f / 64.0f), aw[h * 2 * KK + k], logit);
      logit = fmaf(smm[ll][k], aw[h * 2 * KK + KK + k], logit);
    }
    nw[ll][h].y = 1.0f + 1.0f / (1.0f + __expf(-logit));
  }

  // per-lane tc weights (overlaps with step 1b)
  float tw0[KK], tw1[KK];
#pragma unroll
  for (int k = 0; k < KK; ++k) {
    tw0[k] = tc_w[(2 * lh) * KK + k];
    tw1[k] = tc_w[(2 * lh + 1) * KK + k];
  }
  const float tb0 = tc_b[2 * lh];
  const float tb1 = tc_b[2 * lh + 1];
  __syncthreads();

  // step 2: weighted gather-reduce. Half-wave per l -> 128 B/gather segment.
  const unsigned* xtb = (const unsigned*)xt + (size_t)b * NPOS * 32;
#pragma unroll
  for (int j = 0; j < 4; ++j) {
    const int ll = wid * 8 + j * 2 + half;
    float a0 = 0.0f, a1 = 0.0f;
#pragma unroll
    for (int k = 0; k < KK; ++k) {
      const float2 p = nw[ll][k];       // broadcast ds_read_b64
      const int   n  = __float_as_int(p.x);
      const float wk = p.y;
      const unsigned u = xtb[(size_t)n * 32 + lh];
      a0 = fmaf(wk * tw0[k], __uint_as_float(u << 16), a0);
      a1 = fmaf(wk * tw1[k], __uint_as_float(u & 0xffff0000u), a1);
    }
    res[2 * lh][ll]     = a0 + tb0;
    res[2 * lh + 1][ll] = a1 + tb1;
  }
  __syncthreads();

  // step 3: 64c x 32l tile out, float4 per store, 2 per thread.
  const int c  = t >> 2;
  const int q4 = t & 3;
#pragma unroll
  for (int rep = 0; rep < 2; ++rep) {
    const int lo = rep * 16 + q4 * 4;
    float4 o;
    o.x = res[c][lo + 0];
    o.y = res[c][lo + 1];
    o.z = res[c][lo + 2];
    o.w = res[c][lo + 3];
    *(float4*)(out + ((size_t)b * CC + c) * LL + l_base + lo) = o;
  }
}

extern "C" void kernel_launch(void* const* d_in, const int* in_sizes, int n_in,
                              void* d_out, int out_size, void* d_ws, size_t ws_size,
                              hipStream_t stream) {
  const float* x     = (const float*)d_in[0];
  const int*   idx   = (const int*)d_in[1];
  const float* att_w = (const float*)d_in[2];
  const float* att_b = (const float*)d_in[3];
  const float* tc_w  = (const float*)d_in[4];
  const float* tc_b  = (const float*)d_in[5];
  float* out = (float*)d_out;

  // ws carve: xt bf16 (2*N*64, 168 MB) | stats float2 (2*N, 10.5 MB)
  //           | mask (N bytes, 0.65 MB)
  __hip_bfloat16* xt = (__hip_bfloat16*)d_ws;
  float2* stats = (float2*)(xt + (size_t)2 * NPOS * CC);
  unsigned char* mask = (unsigned char*)(stats + (size_t)2 * NPOS);

  k_mask_zero<<<NPOS / (16 * 256), 256, 0, stream>>>((uint4*)mask);
  k_mask_set<<<(LL * KK + 255) / 256, 256, 0, stream>>>(idx, mask);

  dim3 g1(HWSZ / 64, 2 * QQ);
  k_transpose_stats<<<g1, 256, 0, stream>>>(x, mask, xt, stats);

  dim3 g2(2 * (LL / 32));
  k_gather_out<<<g2, 256, 0, stream>>>(xt, stats, idx, att_w, att_b,
                                       tc_w, tc_b, out);
}